// Round 2
// baseline (330.090 us; speedup 1.0000x reference)
//
#include <hip/hip_runtime.h>

// Problem constants
#define B_  512
#define T_  256
#define C_  256
#define H_  64
#define BT_ (B_ * T_)   // 131072

typedef unsigned short u16;
typedef __attribute__((ext_vector_type(8))) __bf16 bf16x8;
typedef __attribute__((ext_vector_type(8))) u16 u16x8;
typedef __attribute__((ext_vector_type(4))) float f32x4;

__device__ __forceinline__ u16 f2bf(float f) {
  union { float f; unsigned u; } v; v.f = f;
  unsigned r = v.u + 0x7fffu + ((v.u >> 16) & 1u);   // RNE
  return (u16)(r >> 16);
}

__device__ __forceinline__ f32x4 mfma16(bf16x8 a, bf16x8 b, f32x4 c) {
  return __builtin_amdgcn_mfma_f32_16x16x32_bf16(a, b, c, 0, 0, 0);
}

// ---------------------------------------------------------------------------
// Kernel 0: W [C][H] fp32 x3  ->  wt bf16 [3][H][C]  (transposed, K-contig)
// ---------------------------------------------------------------------------
__global__ __launch_bounds__(256) void wconv_kernel(
    const float* __restrict__ Wq, const float* __restrict__ Wk,
    const float* __restrict__ Wv, u16* __restrict__ wt) {
  int idx = blockIdx.x * 256 + threadIdx.x;      // 0 .. 49151
  int w   = idx >> 14;                            // / (64*256)
  int rem = idx & 16383;
  int h   = rem >> 8;
  int c   = rem & 255;
  const float* W = (w == 0) ? Wq : (w == 1) ? Wk : Wv;
  wt[idx] = f2bf(W[c * H_ + h]);
}

// ---------------------------------------------------------------------------
// Kernel 1: QKV projection. Block = 64 rows, 4 waves x 16 rows.
// A-frags straight from global x (fp32->bf16), B-frags from wt (L1/L2-hot).
// Outputs: q,k bf16 [BT][64]; v transposed bf16 [B][64][T].
// ---------------------------------------------------------------------------
__global__ __launch_bounds__(256) void qkv_kernel(
    const float* __restrict__ x, const u16* __restrict__ wt,
    u16* __restrict__ qo, u16* __restrict__ ko, u16* __restrict__ vto) {
  const int wave = threadIdx.x >> 6, lane = threadIdx.x & 63;
  const int lr = lane & 15, lg = lane >> 4;
  const int row = blockIdx.x * 64 + wave * 16 + lr;

  const f32x4 fzero = {0.f, 0.f, 0.f, 0.f};
  f32x4 acc[12];
#pragma unroll
  for (int j = 0; j < 12; ++j) acc[j] = fzero;

  const float* xp = x + row * C_ + lg * 8;
#pragma unroll
  for (int kk = 0; kk < 8; ++kk) {
    float4 a0 = *(const float4*)(xp + kk * 32);
    float4 a1 = *(const float4*)(xp + kk * 32 + 4);
    u16x8 au;
    au[0] = f2bf(a0.x); au[1] = f2bf(a0.y); au[2] = f2bf(a0.z); au[3] = f2bf(a0.w);
    au[4] = f2bf(a1.x); au[5] = f2bf(a1.y); au[6] = f2bf(a1.z); au[7] = f2bf(a1.w);
    bf16x8 af = __builtin_bit_cast(bf16x8, au);
#pragma unroll
    for (int j = 0; j < 12; ++j) {
      const u16* wp = wt + ((j >> 2) * 64 + (j & 3) * 16 + lr) * C_ + kk * 32 + lg * 8;
      bf16x8 bf = *(const bf16x8*)wp;
      acc[j] = mfma16(af, bf, acc[j]);
    }
  }

  const int rbase = blockIdx.x * 64 + wave * 16 + lg * 4;
#pragma unroll
  for (int j = 0; j < 12; ++j) {
    const int wsel = j >> 2;
    const int h = (j & 3) * 16 + lr;
#pragma unroll
    for (int i = 0; i < 4; ++i) {
      const int r = rbase + i;
      u16 val = f2bf(acc[j][i]);
      if (wsel == 0) {
        qo[r * H_ + h] = val;
      } else if (wsel == 1) {
        ko[r * H_ + h] = val;
      } else {
        int bb = r >> 8, tt = r & 255;
        vto[(bb * H_ + h) * T_ + tt] = val;
      }
    }
  }
}

// ---------------------------------------------------------------------------
// Kernel 2: causal attention, one block per batch, 4 waves.
// Wave handles chunks (32*w) and (32*(7-w)) -> 5 KV-tiles each (balanced).
// K in LDS [256][72] (pad), Vt in LDS [64][264] (pad), P via per-wave LDS.
// ---------------------------------------------------------------------------
__global__ __launch_bounds__(256) void attn_kernel(
    const u16* __restrict__ q, const u16* __restrict__ k,
    const u16* __restrict__ vt, float* __restrict__ out) {
  __shared__ u16 sK[256 * 72];     // 36864 B
  __shared__ u16 sVt[64 * 264];    // 33792 B
  __shared__ u16 sP[4 * 32 * 72];  // 18432 B

  const int b = blockIdx.x;
  const int tid = threadIdx.x;

  // stage K [256][64] -> sK [256][72]
  const u16* kb = k + b * (T_ * H_);
  for (int c = tid; c < 2048; c += 256) {
    int r = c >> 3, off = (c & 7) * 8;
    *(u16x8*)&sK[r * 72 + off] = *(const u16x8*)(kb + c * 8);
  }
  // stage Vt [64][256] -> sVt [64][264]
  const u16* vb = vt + b * (H_ * T_);
  for (int c = tid; c < 2048; c += 256) {
    int r = c >> 5, off = (c & 31) * 8;
    *(u16x8*)&sVt[r * 264 + off] = *(const u16x8*)(vb + c * 8);
  }
  __syncthreads();

  const int wave = tid >> 6, lane = tid & 63;
  const int lr = lane & 15, lg = lane >> 4;
  u16* sPw = sP + wave * 32 * 72;
  const u16* qb = q + b * (T_ * H_);
  float* ob = out + b * (T_ * H_);

  const f32x4 fzero = {0.f, 0.f, 0.f, 0.f};

#pragma unroll
  for (int ch = 0; ch < 2; ++ch) {
    const int chunk = (ch == 0) ? wave : (7 - wave);
    const int r0 = 32 * chunk;
    const int tl = (r0 + 31) >> 6;   // last (diagonal) KV tile index

    // Q fragments for this chunk: rows r0..r0+31, in registers
    bf16x8 qf[2][2];
#pragma unroll
    for (int mt = 0; mt < 2; ++mt)
#pragma unroll
      for (int ks = 0; ks < 2; ++ks)
        qf[mt][ks] = *(const bf16x8*)(qb + (r0 + mt * 16 + lr) * H_ + ks * 32 + lg * 8);

    f32x4 o[2][4];
#pragma unroll
    for (int mt = 0; mt < 2; ++mt)
#pragma unroll
      for (int ht = 0; ht < 4; ++ht) o[mt][ht] = fzero;
    float mrow[2][4], lrow[2][4];
#pragma unroll
    for (int mt = 0; mt < 2; ++mt)
#pragma unroll
      for (int i = 0; i < 4; ++i) { mrow[mt][i] = -1e30f; lrow[mt][i] = 0.f; }

    for (int t = 0; t <= tl; ++t) {
      // ---- S = Q K^T for this 32x64 tile ----
      f32x4 s[2][4];
#pragma unroll
      for (int mt = 0; mt < 2; ++mt)
#pragma unroll
        for (int nt = 0; nt < 4; ++nt) s[mt][nt] = fzero;
#pragma unroll
      for (int ks = 0; ks < 2; ++ks) {
#pragma unroll
        for (int nt = 0; nt < 4; ++nt) {
          bf16x8 kf = *(const bf16x8*)&sK[(t * 64 + nt * 16 + lr) * 72 + ks * 32 + lg * 8];
          s[0][nt] = mfma16(qf[0][ks], kf, s[0][nt]);
          s[1][nt] = mfma16(qf[1][ks], kf, s[1][nt]);
        }
      }

      // ---- online softmax update ----
      const bool diag = (t == tl);
#pragma unroll
      for (int mt = 0; mt < 2; ++mt) {
#pragma unroll
        for (int i = 0; i < 4; ++i) {
          const int r = r0 + mt * 16 + lg * 4 + i;
          float pv[4];
          float mx = -1e30f;
#pragma unroll
          for (int nt = 0; nt < 4; ++nt) {
            float v = s[mt][nt][i] * 0.0625f;   // * C^-0.5
            if (diag && (t * 64 + nt * 16 + lr > r)) v = -1e30f;
            pv[nt] = v;
            mx = fmaxf(mx, v);
          }
          mx = fmaxf(mx, __shfl_xor(mx, 1));
          mx = fmaxf(mx, __shfl_xor(mx, 2));
          mx = fmaxf(mx, __shfl_xor(mx, 4));
          mx = fmaxf(mx, __shfl_xor(mx, 8));
          float mnew = fmaxf(mrow[mt][i], mx);
          float alpha = __expf(mrow[mt][i] - mnew);
          mrow[mt][i] = mnew;
          float rs = 0.f;
#pragma unroll
          for (int nt = 0; nt < 4; ++nt) {
            float p = __expf(pv[nt] - mnew);
            rs += p;
            sPw[(mt * 16 + lg * 4 + i) * 72 + nt * 16 + lr] = f2bf(p);
          }
          rs += __shfl_xor(rs, 1);
          rs += __shfl_xor(rs, 2);
          rs += __shfl_xor(rs, 4);
          rs += __shfl_xor(rs, 8);
          lrow[mt][i] = lrow[mt][i] * alpha + rs;
#pragma unroll
          for (int ht = 0; ht < 4; ++ht) o[mt][ht][i] *= alpha;
        }
      }

      // make P LDS writes visible to (other lanes') reads; per-wave only
      __builtin_amdgcn_wave_barrier();

      // ---- O += P V ----
#pragma unroll
      for (int ks2 = 0; ks2 < 2; ++ks2) {
        bf16x8 pf0 = *(const bf16x8*)&sPw[(0 + lr) * 72 + ks2 * 32 + lg * 8];
        bf16x8 pf1 = *(const bf16x8*)&sPw[(16 + lr) * 72 + ks2 * 32 + lg * 8];
#pragma unroll
        for (int ht = 0; ht < 4; ++ht) {
          bf16x8 vf = *(const bf16x8*)&sVt[(ht * 16 + lr) * 264 + t * 64 + ks2 * 32 + lg * 8];
          o[0][ht] = mfma16(pf0, vf, o[0][ht]);
          o[1][ht] = mfma16(pf1, vf, o[1][ht]);
        }
      }
      // keep next tile's P writes from moving above these reads
      __builtin_amdgcn_wave_barrier();
    }

    // ---- epilogue: normalize and store fp32 ----
#pragma unroll
    for (int mt = 0; mt < 2; ++mt) {
#pragma unroll
      for (int i = 0; i < 4; ++i) {
        const float inv = 1.f / lrow[mt][i];
        const int r = r0 + mt * 16 + lg * 4 + i;
#pragma unroll
        for (int ht = 0; ht < 4; ++ht) {
          ob[r * H_ + ht * 16 + lr] = o[mt][ht][i] * inv;
        }
      }
    }
  }
}

// ---------------------------------------------------------------------------
extern "C" void kernel_launch(void* const* d_in, const int* in_sizes, int n_in,
                              void* d_out, int out_size, void* d_ws, size_t ws_size,
                              hipStream_t stream) {
  const float* x  = (const float*)d_in[0];
  const float* Wq = (const float*)d_in[1];
  const float* Wk = (const float*)d_in[2];
  const float* Wv = (const float*)d_in[3];
  float* out = (float*)d_out;

  u16* ws = (u16*)d_ws;
  u16* wt = ws;                          // 3*64*256         = 49152 elems
  u16* qb = ws + 49152;                  // BT*64            = 8388608
  u16* kb = qb + (size_t)BT_ * H_;       // 8388608
  u16* vb = kb + (size_t)BT_ * H_;       // 8388608  (transposed [B][64][T])

  wconv_kernel<<<192, 256, 0, stream>>>(Wq, Wk, Wv, wt);
  qkv_kernel<<<BT_ / 64, 256, 0, stream>>>(x, wt, qb, kb, vb);
  attn_kernel<<<B_, 256, 0, stream>>>(qb, kb, vb, out);
}

// Round 4
// 262.643 us; speedup vs baseline: 1.2568x; 1.2568x over previous
//
#include <hip/hip_runtime.h>

// Problem constants
#define B_  512
#define T_  256
#define C_  256
#define H_  64
#define BT_ (B_ * T_)   // 131072

typedef unsigned short u16;
typedef __attribute__((ext_vector_type(8))) __bf16 bf16x8;
typedef __attribute__((ext_vector_type(8))) u16 u16x8;
typedef __attribute__((ext_vector_type(4))) float f32x4;

__device__ __forceinline__ u16 f2bf(float f) {
  union { float f; unsigned u; } v; v.f = f;
  unsigned r = v.u + 0x7fffu + ((v.u >> 16) & 1u);   // RNE
  return (u16)(r >> 16);
}

__device__ __forceinline__ f32x4 mfma16(bf16x8 a, bf16x8 b, f32x4 c) {
  return __builtin_amdgcn_mfma_f32_16x16x32_bf16(a, b, c, 0, 0, 0);
}

// ---------------------------------------------------------------------------
// Kernel 0: W [C][H] fp32 x3  ->  wt bf16 [3][H][C]  (transposed, K-contig)
// ---------------------------------------------------------------------------
__global__ __launch_bounds__(256) void wconv_kernel(
    const float* __restrict__ Wq, const float* __restrict__ Wk,
    const float* __restrict__ Wv, u16* __restrict__ wt) {
  int idx = blockIdx.x * 256 + threadIdx.x;      // 0 .. 49151
  int w   = idx >> 14;                            // / (64*256)
  int rem = idx & 16383;
  int h   = rem >> 8;
  int c   = rem & 255;
  const float* W = (w == 0) ? Wq : (w == 1) ? Wk : Wv;
  wt[idx] = f2bf(W[c * H_ + h]);
}

// ---------------------------------------------------------------------------
// Kernel 1 (v2): QKV projection as LDS-staged GEMM.
// Block = 128 rows x 192 cols, 4 waves (wave = 32 rows). K-loop: 8 steps of 32.
// B (wt) slice [192][32] bf16 staged in LDS double-buffered (12KB x2):
//   kills the 3.2GB of L2 B-frag re-reads that made v1 latency-bound.
// A (x) direct from global with 1-step register prefetch (T14 issue-early).
// ---------------------------------------------------------------------------
__global__ __launch_bounds__(256) void qkv_kernel(
    const float* __restrict__ x, const u16* __restrict__ wt,
    u16* __restrict__ qo, u16* __restrict__ ko, u16* __restrict__ vto) {
  __shared__ u16 sB[2][192 * 32];   // [buf][row 0..191][k-slot 0..31], 24 KiB

  const int tid  = threadIdx.x;
  const int wave = tid >> 6, lane = tid & 63;
  const int lr = lane & 15, lg = lane >> 4;
  const int row0 = blockIdx.x * 128;

  const f32x4 fzero = {0.f, 0.f, 0.f, 0.f};
  f32x4 acc[2][12];
#pragma unroll
  for (int mt = 0; mt < 2; ++mt)
#pragma unroll
    for (int nt = 0; nt < 12; ++nt) acc[mt][nt] = fzero;

  // A-frag source rows for this wave (16x16x32 A-layout: row=lr, k=lg*8..+8)
  const float* xp0 = x + (size_t)(row0 + wave * 32 + lr) * C_ + lg * 8;
  const float* xp1 = xp0 + 16 * C_;

  float4 aA[2][2][2];    // [buf][mt][half]
  u16x8  breg[2][3];     // [buf][i] staged B slots

#define LOAD_A(buf, kk)                                     \
  {                                                         \
    aA[buf][0][0] = *(const float4*)(xp0 + (kk) * 32);      \
    aA[buf][0][1] = *(const float4*)(xp0 + (kk) * 32 + 4);  \
    aA[buf][1][0] = *(const float4*)(xp1 + (kk) * 32);      \
    aA[buf][1][1] = *(const float4*)(xp1 + (kk) * 32 + 4);  \
  }

  // B slice: wt[row 0..191][kk*32 .. +32].  768 16B-slots, thread stages 3.
#define LOAD_B(buf, kk)                                                        \
  {                                                                            \
    _Pragma("unroll") for (int i = 0; i < 3; ++i) {                            \
      int d = i * 256 + tid;                                                   \
      breg[buf][i] = *(const u16x8*)(wt + (d >> 2) * C_ + (kk) * 32 + (d & 3) * 8); \
    }                                                                          \
  }

#define WRITE_B(buf)                                        \
  {                                                         \
    _Pragma("unroll") for (int i = 0; i < 3; ++i) {         \
      int d = i * 256 + tid;                                \
      *(u16x8*)&sB[buf][d * 8] = breg[buf][i];              \
    }                                                       \
  }

#define COMPUTE(buf)                                                       \
  {                                                                        \
    bf16x8 af[2];                                                          \
    _Pragma("unroll") for (int mt = 0; mt < 2; ++mt) {                     \
      u16x8 au;                                                            \
      au[0] = f2bf(aA[buf][mt][0].x); au[1] = f2bf(aA[buf][mt][0].y);      \
      au[2] = f2bf(aA[buf][mt][0].z); au[3] = f2bf(aA[buf][mt][0].w);      \
      au[4] = f2bf(aA[buf][mt][1].x); au[5] = f2bf(aA[buf][mt][1].y);      \
      au[6] = f2bf(aA[buf][mt][1].z); au[7] = f2bf(aA[buf][mt][1].w);      \
      af[mt] = __builtin_bit_cast(bf16x8, au);                             \
    }                                                                      \
    _Pragma("unroll") for (int nt = 0; nt < 12; ++nt) {                    \
      bf16x8 bf = *(const bf16x8*)&sB[buf][(nt * 16 + lr) * 32 + lg * 8];  \
      acc[0][nt] = mfma16(af[0], bf, acc[0][nt]);                          \
      acc[1][nt] = mfma16(af[1], bf, acc[1][nt]);                          \
    }                                                                      \
  }

  LOAD_A(0, 0);
  LOAD_B(0, 0);
  WRITE_B(0);
  __syncthreads();

#pragma unroll
  for (int t = 0; t < 8; ++t) {
    const int cur = t & 1, nxt = cur ^ 1;
    if (t < 7) {
      LOAD_A(nxt, t + 1);      // issue early: latency hides under MFMAs
      LOAD_B(nxt, t + 1);
    }
    COMPUTE(cur);
    if (t < 7) WRITE_B(nxt);   // write late (after data arrives)
    __syncthreads();
  }

  // Epilogue: C-layout col=lr (h within 16-tile), row=lg*4+i.
  const int rbase = row0 + wave * 32 + lg * 4;
#pragma unroll
  for (int nt = 0; nt < 12; ++nt) {
    const int wsel = nt >> 2;
    const int h = (nt & 3) * 16 + lr;
#pragma unroll
    for (int mt = 0; mt < 2; ++mt) {
#pragma unroll
      for (int i = 0; i < 4; ++i) {
        const int r = rbase + mt * 16 + i;
        u16 val = f2bf(acc[mt][nt][i]);
        if (wsel == 0) {
          qo[r * H_ + h] = val;
        } else if (wsel == 1) {
          ko[r * H_ + h] = val;
        } else {
          int bb = r >> 8, tt = r & 255;
          vto[(bb * H_ + h) * T_ + tt] = val;
        }
      }
    }
  }
#undef LOAD_A
#undef LOAD_B
#undef WRITE_B
#undef COMPUTE
}

// ---------------------------------------------------------------------------
// Kernel 2: causal attention, one block per batch, 4 waves.  (UNCHANGED v1)
// Wave handles chunks (32*w) and (32*(7-w)) -> 5 KV-tiles each (balanced).
// K in LDS [256][72] (pad), Vt in LDS [64][264] (pad), P via per-wave LDS.
// ---------------------------------------------------------------------------
__global__ __launch_bounds__(256) void attn_kernel(
    const u16* __restrict__ q, const u16* __restrict__ k,
    const u16* __restrict__ vt, float* __restrict__ out) {
  __shared__ u16 sK[256 * 72];     // 36864 B
  __shared__ u16 sVt[64 * 264];    // 33792 B
  __shared__ u16 sP[4 * 32 * 72];  // 18432 B

  const int b = blockIdx.x;
  const int tid = threadIdx.x;

  // stage K [256][64] -> sK [256][72]
  const u16* kb = k + b * (T_ * H_);
  for (int c = tid; c < 2048; c += 256) {
    int r = c >> 3, off = (c & 7) * 8;
    *(u16x8*)&sK[r * 72 + off] = *(const u16x8*)(kb + c * 8);
  }
  // stage Vt [64][256] -> sVt [64][264]
  const u16* vb = vt + b * (H_ * T_);
  for (int c = tid; c < 2048; c += 256) {
    int r = c >> 5, off = (c & 31) * 8;
    *(u16x8*)&sVt[r * 264 + off] = *(const u16x8*)(vb + c * 8);
  }
  __syncthreads();

  const int wave = tid >> 6, lane = tid & 63;
  const int lr = lane & 15, lg = lane >> 4;
  u16* sPw = sP + wave * 32 * 72;
  const u16* qb = q + b * (T_ * H_);
  float* ob = out + b * (T_ * H_);

  const f32x4 fzero = {0.f, 0.f, 0.f, 0.f};

#pragma unroll
  for (int ch = 0; ch < 2; ++ch) {
    const int chunk = (ch == 0) ? wave : (7 - wave);
    const int r0 = 32 * chunk;
    const int tl = (r0 + 31) >> 6;   // last (diagonal) KV tile index

    // Q fragments for this chunk: rows r0..r0+31, in registers
    bf16x8 qf[2][2];
#pragma unroll
    for (int mt = 0; mt < 2; ++mt)
#pragma unroll
      for (int ks = 0; ks < 2; ++ks)
        qf[mt][ks] = *(const bf16x8*)(qb + (r0 + mt * 16 + lr) * H_ + ks * 32 + lg * 8);

    f32x4 o[2][4];
#pragma unroll
    for (int mt = 0; mt < 2; ++mt)
#pragma unroll
      for (int ht = 0; ht < 4; ++ht) o[mt][ht] = fzero;
    float mrow[2][4], lrow[2][4];
#pragma unroll
    for (int mt = 0; mt < 2; ++mt)
#pragma unroll
      for (int i = 0; i < 4; ++i) { mrow[mt][i] = -1e30f; lrow[mt][i] = 0.f; }

    for (int t = 0; t <= tl; ++t) {
      // ---- S = Q K^T for this 32x64 tile ----
      f32x4 s[2][4];
#pragma unroll
      for (int mt = 0; mt < 2; ++mt)
#pragma unroll
        for (int nt = 0; nt < 4; ++nt) s[mt][nt] = fzero;
#pragma unroll
      for (int ks = 0; ks < 2; ++ks) {
#pragma unroll
        for (int nt = 0; nt < 4; ++nt) {
          bf16x8 kf = *(const bf16x8*)&sK[(t * 64 + nt * 16 + lr) * 72 + ks * 32 + lg * 8];
          s[0][nt] = mfma16(qf[0][ks], kf, s[0][nt]);
          s[1][nt] = mfma16(qf[1][ks], kf, s[1][nt]);
        }
      }

      // ---- online softmax update ----
      const bool diag = (t == tl);
#pragma unroll
      for (int mt = 0; mt < 2; ++mt) {
#pragma unroll
        for (int i = 0; i < 4; ++i) {
          const int r = r0 + mt * 16 + lg * 4 + i;
          float pv[4];
          float mx = -1e30f;
#pragma unroll
          for (int nt = 0; nt < 4; ++nt) {
            float v = s[mt][nt][i] * 0.0625f;   // * C^-0.5
            if (diag && (t * 64 + nt * 16 + lr > r)) v = -1e30f;
            pv[nt] = v;
            mx = fmaxf(mx, v);
          }
          mx = fmaxf(mx, __shfl_xor(mx, 1));
          mx = fmaxf(mx, __shfl_xor(mx, 2));
          mx = fmaxf(mx, __shfl_xor(mx, 4));
          mx = fmaxf(mx, __shfl_xor(mx, 8));
          float mnew = fmaxf(mrow[mt][i], mx);
          float alpha = __expf(mrow[mt][i] - mnew);
          mrow[mt][i] = mnew;
          float rs = 0.f;
#pragma unroll
          for (int nt = 0; nt < 4; ++nt) {
            float p = __expf(pv[nt] - mnew);
            rs += p;
            sPw[(mt * 16 + lg * 4 + i) * 72 + nt * 16 + lr] = f2bf(p);
          }
          rs += __shfl_xor(rs, 1);
          rs += __shfl_xor(rs, 2);
          rs += __shfl_xor(rs, 4);
          rs += __shfl_xor(rs, 8);
          lrow[mt][i] = lrow[mt][i] * alpha + rs;
#pragma unroll
          for (int ht = 0; ht < 4; ++ht) o[mt][ht][i] *= alpha;
        }
      }

      // make P LDS writes visible to (other lanes') reads; per-wave only
      __builtin_amdgcn_wave_barrier();

      // ---- O += P V ----
#pragma unroll
      for (int ks2 = 0; ks2 < 2; ++ks2) {
        bf16x8 pf0 = *(const bf16x8*)&sPw[(0 + lr) * 72 + ks2 * 32 + lg * 8];
        bf16x8 pf1 = *(const bf16x8*)&sPw[(16 + lr) * 72 + ks2 * 32 + lg * 8];
#pragma unroll
        for (int ht = 0; ht < 4; ++ht) {
          bf16x8 vf = *(const bf16x8*)&sVt[(ht * 16 + lr) * 264 + t * 64 + ks2 * 32 + lg * 8];
          o[0][ht] = mfma16(pf0, vf, o[0][ht]);
          o[1][ht] = mfma16(pf1, vf, o[1][ht]);
        }
      }
      // keep next tile's P writes from moving above these reads
      __builtin_amdgcn_wave_barrier();
    }

    // ---- epilogue: normalize and store fp32 ----
#pragma unroll
    for (int mt = 0; mt < 2; ++mt) {
#pragma unroll
      for (int i = 0; i < 4; ++i) {
        const float inv = 1.f / lrow[mt][i];
        const int r = r0 + mt * 16 + lg * 4 + i;
#pragma unroll
        for (int ht = 0; ht < 4; ++ht) {
          ob[r * H_ + ht * 16 + lr] = o[mt][ht][i] * inv;
        }
      }
    }
  }
}

// ---------------------------------------------------------------------------
extern "C" void kernel_launch(void* const* d_in, const int* in_sizes, int n_in,
                              void* d_out, int out_size, void* d_ws, size_t ws_size,
                              hipStream_t stream) {
  const float* x  = (const float*)d_in[0];
  const float* Wq = (const float*)d_in[1];
  const float* Wk = (const float*)d_in[2];
  const float* Wv = (const float*)d_in[3];
  float* out = (float*)d_out;

  u16* ws = (u16*)d_ws;
  u16* wt = ws;                          // 3*64*256         = 49152 elems
  u16* qb = ws + 49152;                  // BT*64            = 8388608
  u16* kb = qb + (size_t)BT_ * H_;       // 8388608
  u16* vb = kb + (size_t)BT_ * H_;       // 8388608  (transposed [B][64][T])

  wconv_kernel<<<192, 256, 0, stream>>>(Wq, Wk, Wv, wt);
  qkv_kernel<<<BT_ / 128, 256, 0, stream>>>(x, wt, qb, kb, vb);
  attn_kernel<<<B_, 256, 0, stream>>>(qb, kb, vb, out);
}